// Round 4
// baseline (443.880 us; speedup 1.0000x reference)
//
#include <hip/hip_runtime.h>

#define D 128
#define BN_EPS 1e-5f
#define ELLW 64             // max degree slots (Poisson(12.8): P(deg>64) ~ 1e-24)
#define SPAD 32             // stats padding: 32 floats = 128 B = one cache line

typedef __bf16 bf16_t;
typedef __bf16 bf16x8 __attribute__((ext_vector_type(8)));
typedef __bf16 bf16x4 __attribute__((ext_vector_type(4)));
typedef __bf16 bf16x2 __attribute__((ext_vector_type(2)));
typedef float floatx4 __attribute__((ext_vector_type(4)));

// ===========================================================================
// prep: zero deg[N] + padded stats + barrier counters, x fp32 -> hb bf16,
// swizzle weights to MFMA B-frag order. Grid covers n4 = N*D/4.
// ===========================================================================
__global__ void prep(const float* __restrict__ x, bf16_t* __restrict__ hb,
                     const float* __restrict__ W1, const float* __restrict__ W2,
                     bf16_t* __restrict__ Wsw, int* __restrict__ deg,
                     float* __restrict__ stats, unsigned* __restrict__ bar,
                     int N, int n4) {
  int i = blockIdx.x * blockDim.x + threadIdx.x;
  if (i < n4) {
    float4 v = ((const float4*)x)[i];
    bf16x4 p;
    p[0] = (bf16_t)v.x; p[1] = (bf16_t)v.y; p[2] = (bf16_t)v.z; p[3] = (bf16_t)v.w;
    *(bf16x4*)(hb + (size_t)4 * i) = p;
  }
  if (i < N) deg[i] = 0;
  if (i < 3 * 256 * SPAD) stats[i] = 0.f;     // 24,576 floats (padded, 3 layers)
  if (i < 4 * SPAD) bar[i] = 0u;              // 4 counters, each on own line
  if (i < 6 * 16384) {
    // B-frag order: lane = quad*16 + (n&15) holds B[k=kc*32+quad*8+j][n]
    int mat = i >> 14;
    int kn = i & 16383;
    int k = kn >> 7;
    int n = kn & 127;
    const float* Wm = (mat < 3) ? (W1 + (size_t)mat * 16384)
                                : (W2 + (size_t)(mat - 3) * 16384);
    float v = Wm[kn];
    int f = ((n >> 4) << 2) | (k >> 5);
    int ln = (((k >> 3) & 3) << 4) | (n & 15);
    int j = k & 7;
    Wsw[(size_t)mat * 16384 + ((f << 6) + ln) * 8 + j] = (bf16_t)v;
  }
}

// ===========================================================================
// ell_fill: one-shot ELL build — atomic slot bump + native 4B scatter.
// ===========================================================================
__global__ void ell_fill(const int* __restrict__ src, const int* __restrict__ dst,
                         int* __restrict__ deg, int* __restrict__ ell, int E) {
  int e = blockIdx.x * blockDim.x + threadIdx.x;
  if (e < E) {
    int d = dst[e];
    int slot = atomicAdd(&deg[d], 1);
    if (slot < ELLW) ell[(size_t)d * ELLW + slot] = src[e];
  }
}

// ===========================================================================
// aggregate: z[v] = h[v] + sum_{u in N(v)} h[u] — one wave per node
// (12500 blocks; oversubscription is mandatory for this gather: R5/R8).
// ===========================================================================
__global__ __launch_bounds__(256) void aggregate(
    const bf16_t* __restrict__ h, bf16_t* __restrict__ z,
    const int* __restrict__ ell, const int* __restrict__ deg, int Nn) {
  int node = blockIdx.x * 4 + (threadIdx.x >> 6);
  if (node >= Nn) return;
  int lane = threadIdx.x & 63;
  int off = lane << 1;
  int dg = deg[node]; if (dg > ELLW) dg = ELLW;
  const int* nb = ell + (size_t)node * ELLW;

  bf16x2 sv = *(const bf16x2*)(h + (size_t)node * D + off);
  float a0x = (float)sv[0], a0y = (float)sv[1];
  float a1x = 0.f, a1y = 0.f, a2x = 0.f, a2y = 0.f, a3x = 0.f, a3y = 0.f;
  int e = 0;
  for (; e + 4 <= dg; e += 4) {
    int4 i4 = *(const int4*)(nb + e);
    bf16x2 v0 = *(const bf16x2*)(h + (size_t)i4.x * D + off);
    bf16x2 v1 = *(const bf16x2*)(h + (size_t)i4.y * D + off);
    bf16x2 v2 = *(const bf16x2*)(h + (size_t)i4.z * D + off);
    bf16x2 v3 = *(const bf16x2*)(h + (size_t)i4.w * D + off);
    a0x += (float)v0[0]; a0y += (float)v0[1];
    a1x += (float)v1[0]; a1y += (float)v1[1];
    a2x += (float)v2[0]; a2y += (float)v2[1];
    a3x += (float)v3[0]; a3y += (float)v3[1];
  }
  for (; e < dg; ++e) {
    bf16x2 v = *(const bf16x2*)(h + (size_t)nb[e] * D + off);
    a0x += (float)v[0]; a0y += (float)v[1];
  }
  a0x += a1x + a2x + a3x;
  a0y += a1y + a2y + a3y;
  bf16x2 o;
  o[0] = (bf16_t)a0x; o[1] = (bf16_t)a0y;
  *(bf16x2*)(z + (size_t)node * D + off) = o;
}

// ===========================================================================
// mlp_fused: GEMM1 + BN-stats  --manual grid barrier--  BN+ReLU in C-layout
// -> LDS transpose to A-frags -> GEMM2 -> store. Y never leaves registers.
//
// Residency proof: __launch_bounds__(256,4) caps VGPR at 128 -> 4 blocks/CU;
// LDS 18,432 B * 4 = 73.7 KB <= 160 KB. Capacity 1024 >= grid 782.
//
// Stats atomics are PADDED one-per-cacheline (SPAD): R3 showed 200k
// device-scope atomicAdds onto 8 cache lines serialize ~25k RMW/line at the
// coherent point (~50-70 us) — every block's pre-barrier vmcnt(0) drain
// waits on that queue. 32x line spread cuts it to ~782 RMW/line.
// Barrier poll stays RELAXED (acquire-per-poll = buffer_inv storm, R2).
// ===========================================================================
__global__ __launch_bounds__(256, 4) void mlp_fused(
    const bf16_t* __restrict__ Z, float* __restrict__ stats,
    const float* __restrict__ gamma, const float* __restrict__ beta,
    const bf16_t* __restrict__ Wsw1, const float* __restrict__ bias1,
    const bf16_t* __restrict__ Wsw2, const float* __restrict__ bias2,
    void* __restrict__ outp, unsigned* __restrict__ bar,
    int nBlocks, int nStrips, int N, float invN,
    int relu_out, int fp32_out) {
  __shared__ bf16_t T[64][136];
  __shared__ float sred[256];
  const int t = threadIdx.x;
  const int wv = t >> 6;
  const int lane = t & 63;
  const int l15 = lane & 15;
  const int quad = lane >> 4;
  const int strip = blockIdx.x * 4 + wv;
  const bool active = strip < nStrips;

  sred[t] = 0.f;

  // ---- Phase A: GEMM1 (Z @ W1 + b1), Y stays in acc (C-layout) ----
  bf16x8 a[4];
  const int row = strip * 16 + l15;
  if (active && row < N) {
#pragma unroll
    for (int kc = 0; kc < 4; ++kc)
      a[kc] = *(const bf16x8*)(Z + (size_t)row * D + kc * 32 + quad * 8);
  } else {
#pragma unroll
    for (int kc = 0; kc < 4; ++kc)
#pragma unroll
      for (int j = 0; j < 8; ++j) a[kc][j] = (bf16_t)0.f;
  }

  floatx4 acc[8];
#pragma unroll
  for (int nt = 0; nt < 8; ++nt) {
    float bv = bias1[nt * 16 + l15];
    acc[nt] = (floatx4){bv, bv, bv, bv};
  }
#pragma unroll
  for (int nt = 0; nt < 8; ++nt) {
#pragma unroll
    for (int kc = 0; kc < 4; ++kc) {
      bf16x8 b = *(const bf16x8*)(Wsw1 + (size_t)((nt * 4 + kc) * 64 + lane) * 8);
      acc[nt] = __builtin_amdgcn_mfma_f32_16x16x32_bf16(a[kc], b, acc[nt], 0, 0, 0);
    }
  }

  // BN stats: C/D layout col = nt*16+l15, row = quad*4+r
  const int rowBase = strip * 16 + quad * 4;
#pragma unroll
  for (int nt = 0; nt < 8; ++nt) {
    int c = nt * 16 + l15;
    float s = 0.f, q = 0.f;
    if (active) {
#pragma unroll
      for (int r = 0; r < 4; ++r) {
        if (rowBase + r < N) {
          float v = acc[nt][r];
          s += v; q += v * v;
        }
      }
    }
    s += __shfl_xor(s, 16); s += __shfl_xor(s, 32);
    q += __shfl_xor(q, 16); q += __shfl_xor(q, 32);
    if (quad == 0) {
      atomicAdd(&sred[c], s);
      atomicAdd(&sred[128 + c], q);
    }
  }
  __syncthreads();
  // one atomic per stat scalar per block, each scalar on its own cache line
  atomicAdd(&stats[(size_t)t * SPAD], sred[t]);

  // ---- manual grid barrier ------------------------------------------------
  // __syncthreads drains vmcnt(0): this block's stats atomics are acked
  // (at the coherent point) before thread 0 announces arrival.
  __syncthreads();
  if (t == 0) {
    __hip_atomic_fetch_add(bar, 1u, __ATOMIC_RELEASE, __HIP_MEMORY_SCOPE_AGENT);
    int guard = 0;
    // RELAXED poll: plain read-through load, NO cache invalidate per iter.
    while (__hip_atomic_load(bar, __ATOMIC_RELAXED, __HIP_MEMORY_SCOPE_AGENT)
           < (unsigned)nBlocks) {
      __builtin_amdgcn_s_sleep(4);
      if (++guard > (1 << 21)) break;   // anti-hang: fail loud, not forever
    }
    // single acquire: order everything after the observed completion
    __builtin_amdgcn_fence(__ATOMIC_ACQUIRE, "agent");
  }
  __syncthreads();

  // ---- Phase B: stage padded stats into LDS (1 agent-load per thread) ----
  sred[t] = __hip_atomic_load(&stats[(size_t)t * SPAD], __ATOMIC_RELAXED,
                              __HIP_MEMORY_SCOPE_AGENT);
  __syncthreads();

  float bnA[8], bnB[8];
#pragma unroll
  for (int nt = 0; nt < 8; ++nt) {
    int c = nt * 16 + l15;
    float mu = sred[c] * invN;
    float var = fmaxf(sred[128 + c] * invN - mu * mu, 0.f);
    float ai = gamma[c] * rsqrtf(var + BN_EPS);
    bnA[nt] = ai;
    bnB[nt] = beta[c] - mu * ai;
  }

  // transpose BN+ReLU'd Y (C-layout) -> A-frag order via LDS
  const int lr = wv * 16 + quad * 4;
#pragma unroll
  for (int nt = 0; nt < 8; ++nt) {
    int c = nt * 16 + l15;
#pragma unroll
    for (int r = 0; r < 4; ++r)
      T[lr + r][c] = (bf16_t)fmaxf(fmaf(acc[nt][r], bnA[nt], bnB[nt]), 0.f);
  }
  __syncthreads();

  bf16x8 a2[4];
#pragma unroll
  for (int kc = 0; kc < 4; ++kc)
    a2[kc] = *(const bf16x8*)&T[wv * 16 + l15][kc * 32 + quad * 8];

  // ---- GEMM2 ----
#pragma unroll
  for (int nt = 0; nt < 8; ++nt) {
    float bv = bias2[nt * 16 + l15];
    acc[nt] = (floatx4){bv, bv, bv, bv};
  }
#pragma unroll
  for (int nt = 0; nt < 8; ++nt) {
#pragma unroll
    for (int kc = 0; kc < 4; ++kc) {
      bf16x8 b = *(const bf16x8*)(Wsw2 + (size_t)((nt * 4 + kc) * 64 + lane) * 8);
      acc[nt] = __builtin_amdgcn_mfma_f32_16x16x32_bf16(a2[kc], b, acc[nt], 0, 0, 0);
    }
  }

  if (!active) return;
  if (fp32_out) {
    float* out = (float*)outp;
#pragma unroll
    for (int nt = 0; nt < 8; ++nt) {
      int c = nt * 16 + l15;
#pragma unroll
      for (int r = 0; r < 4; ++r) {
        int rw = rowBase + r;
        if (rw < N) {
          float v = acc[nt][r];
          if (relu_out) v = fmaxf(v, 0.f);
          out[(size_t)rw * D + c] = v;
        }
      }
    }
  } else {
    bf16_t* out = (bf16_t*)outp;
#pragma unroll
    for (int nt = 0; nt < 8; ++nt) {
      int c = nt * 16 + l15;
#pragma unroll
      for (int r = 0; r < 4; ++r) {
        int rw = rowBase + r;
        if (rw < N) {
          float v = acc[nt][r];
          if (relu_out) v = fmaxf(v, 0.f);
          out[(size_t)rw * D + c] = (bf16_t)v;
        }
      }
    }
  }
}

// ===========================================================================
extern "C" void kernel_launch(void* const* d_in, const int* in_sizes, int n_in,
                              void* d_out, int out_size, void* d_ws, size_t ws_size,
                              hipStream_t stream) {
  const float* x     = (const float*)d_in[0];
  const float* W1    = (const float*)d_in[1];
  const float* b1    = (const float*)d_in[2];
  const float* gamma = (const float*)d_in[3];
  const float* beta  = (const float*)d_in[4];
  const float* W2    = (const float*)d_in[5];
  const float* b2    = (const float*)d_in[6];
  const int*   ei    = (const int*)d_in[7];

  const int N = in_sizes[0] / D;
  const int E = in_sizes[7] / 2;
  const int* src = ei;
  const int* dst = ei + E;

  char* ws = (char*)d_ws;
  size_t bufBytes = (size_t)N * D * sizeof(bf16_t);        // 12.8 MB
  bf16_t* hb   = (bf16_t*)ws;                               // h (bf16)
  bf16_t* zb   = (bf16_t*)(ws + bufBytes);                  // z (bf16)
  // slot 3 (old Yf) left reserved to preserve layout
  int*    ell  = (int*)(ws + 3 * bufBytes);                 // N*64 int = 12.8 MB
  int*    deg  = (int*)((char*)ell + (size_t)N * ELLW * sizeof(int));
  float*  stats = (float*)((char*)deg + (size_t)N * sizeof(int));   // 3*256*SPAD
  unsigned* bar = (unsigned*)(stats + 3 * 256 * SPAD);      // 4 padded counters
  bf16_t* Wsw  = (bf16_t*)(bar + 4 * SPAD);                 // 6*16384 bf16

  const int n4 = N * D / 4;
  const int prepBlocks = (n4 + 255) / 256;
  const int eb = (E + 255) / 256;
  const int aggBlocks = (N + 3) / 4;
  const int nStrips = (N + 15) / 16;
  const int gemmBlocks = (nStrips + 3) / 4;                 // 782 <= 1024 capacity
  const float invN = 1.f / (float)N;

  prep<<<prepBlocks, 256, 0, stream>>>(x, hb, W1, W2, Wsw, deg, stats, bar, N, n4);
  ell_fill<<<eb, 256, 0, stream>>>(src, dst, deg, ell, E);

  for (int i = 0; i < 3; ++i) {
    aggregate<<<aggBlocks, 256, 0, stream>>>(hb, zb, ell, deg, N);
    void* Ob = (i == 2) ? d_out : (void*)hb;
    mlp_fused<<<gemmBlocks, 256, 0, stream>>>(
        zb, stats + (size_t)i * 256 * SPAD,
        gamma + (size_t)i * D, beta + (size_t)i * D,
        Wsw + (size_t)i * 16384, b1 + (size_t)i * D,
        Wsw + (size_t)(i + 3) * 16384, b2 + (size_t)i * D,
        Ob, bar + (size_t)i * SPAD, gemmBlocks, nStrips, N, invN,
        (i < 2) ? 1 : 0, (i == 2) ? 1 : 0);
  }
}

// Round 5
// 349.274 us; speedup vs baseline: 1.2709x; 1.2709x over previous
//
#include <hip/hip_runtime.h>

#define D 128
#define BN_EPS 1e-5f
#define ELLW 64             // max degree slots (Poisson(12.8): P(deg>64) ~ 1e-24)

typedef __bf16 bf16_t;
typedef __bf16 bf16x8 __attribute__((ext_vector_type(8)));
typedef __bf16 bf16x4 __attribute__((ext_vector_type(4)));
typedef __bf16 bf16x2 __attribute__((ext_vector_type(2)));
typedef float floatx4 __attribute__((ext_vector_type(4)));

// ===========================================================================
// prep: zero deg[N] + stats[768], x fp32 -> hb bf16, swizzle weights to
// MFMA B-frag order. Grid covers n4 = N*D/4 (largest range).
// ===========================================================================
__global__ void prep(const float* __restrict__ x, bf16_t* __restrict__ hb,
                     const float* __restrict__ W1, const float* __restrict__ W2,
                     bf16_t* __restrict__ Wsw, int* __restrict__ deg,
                     float* __restrict__ stats, int N, int n4) {
  int i = blockIdx.x * blockDim.x + threadIdx.x;
  if (i < n4) {
    float4 v = ((const float4*)x)[i];
    bf16x4 p;
    p[0] = (bf16_t)v.x; p[1] = (bf16_t)v.y; p[2] = (bf16_t)v.z; p[3] = (bf16_t)v.w;
    *(bf16x4*)(hb + (size_t)4 * i) = p;
  }
  if (i < N) deg[i] = 0;
  if (i < 768) stats[i] = 0.f;
  if (i < 6 * 16384) {
    // B-frag order: lane = quad*16 + (n&15) holds B[k=kc*32+quad*8+j][n]
    int mat = i >> 14;
    int kn = i & 16383;
    int k = kn >> 7;
    int n = kn & 127;
    const float* Wm = (mat < 3) ? (W1 + (size_t)mat * 16384)
                                : (W2 + (size_t)(mat - 3) * 16384);
    float v = Wm[kn];
    int f = ((n >> 4) << 2) | (k >> 5);
    int ln = (((k >> 3) & 3) << 4) | (n & 15);
    int j = k & 7;
    Wsw[(size_t)mat * 16384 + ((f << 6) + ln) * 8 + j] = (bf16_t)v;
  }
}

// ===========================================================================
// ell_fill: one-shot ELL build — atomic slot bump + native 4B scatter.
// ===========================================================================
__global__ void ell_fill(const int* __restrict__ src, const int* __restrict__ dst,
                         int* __restrict__ deg, int* __restrict__ ell, int E) {
  int e = blockIdx.x * blockDim.x + threadIdx.x;
  if (e < E) {
    int d = dst[e];
    int slot = atomicAdd(&deg[d], 1);
    if (slot < ELLW) ell[(size_t)d * ELLW + slot] = src[e];
  }
}

// ===========================================================================
// aggregate: z[v] = h[v] + sum_{u in N(v)} h[u] — one wave per node
// (12500 blocks; oversubscription is mandatory for this gather: R5/R8).
// ILP-8: 8 outstanding row-gathers per iteration (latency-bound gather).
// ===========================================================================
__global__ __launch_bounds__(256) void aggregate(
    const bf16_t* __restrict__ h, bf16_t* __restrict__ z,
    const int* __restrict__ ell, const int* __restrict__ deg, int Nn) {
  int node = blockIdx.x * 4 + (threadIdx.x >> 6);
  if (node >= Nn) return;
  int lane = threadIdx.x & 63;
  int off = lane << 1;
  int dg = deg[node]; if (dg > ELLW) dg = ELLW;
  const int* nb = ell + (size_t)node * ELLW;

  bf16x2 sv = *(const bf16x2*)(h + (size_t)node * D + off);
  float a0x = (float)sv[0], a0y = (float)sv[1];
  float a1x = 0.f, a1y = 0.f, a2x = 0.f, a2y = 0.f, a3x = 0.f, a3y = 0.f;
  int e = 0;
  for (; e + 8 <= dg; e += 8) {
    int4 ia = *(const int4*)(nb + e);
    int4 ib = *(const int4*)(nb + e + 4);
    bf16x2 v0 = *(const bf16x2*)(h + (size_t)ia.x * D + off);
    bf16x2 v1 = *(const bf16x2*)(h + (size_t)ia.y * D + off);
    bf16x2 v2 = *(const bf16x2*)(h + (size_t)ia.z * D + off);
    bf16x2 v3 = *(const bf16x2*)(h + (size_t)ia.w * D + off);
    bf16x2 v4 = *(const bf16x2*)(h + (size_t)ib.x * D + off);
    bf16x2 v5 = *(const bf16x2*)(h + (size_t)ib.y * D + off);
    bf16x2 v6 = *(const bf16x2*)(h + (size_t)ib.z * D + off);
    bf16x2 v7 = *(const bf16x2*)(h + (size_t)ib.w * D + off);
    a0x += (float)v0[0]; a0y += (float)v0[1];
    a1x += (float)v1[0]; a1y += (float)v1[1];
    a2x += (float)v2[0]; a2y += (float)v2[1];
    a3x += (float)v3[0]; a3y += (float)v3[1];
    a0x += (float)v4[0]; a0y += (float)v4[1];
    a1x += (float)v5[0]; a1y += (float)v5[1];
    a2x += (float)v6[0]; a2y += (float)v6[1];
    a3x += (float)v7[0]; a3y += (float)v7[1];
  }
  for (; e + 4 <= dg; e += 4) {
    int4 i4 = *(const int4*)(nb + e);
    bf16x2 v0 = *(const bf16x2*)(h + (size_t)i4.x * D + off);
    bf16x2 v1 = *(const bf16x2*)(h + (size_t)i4.y * D + off);
    bf16x2 v2 = *(const bf16x2*)(h + (size_t)i4.z * D + off);
    bf16x2 v3 = *(const bf16x2*)(h + (size_t)i4.w * D + off);
    a0x += (float)v0[0]; a0y += (float)v0[1];
    a1x += (float)v1[0]; a1y += (float)v1[1];
    a2x += (float)v2[0]; a2y += (float)v2[1];
    a3x += (float)v3[0]; a3y += (float)v3[1];
  }
  for (; e < dg; ++e) {
    bf16x2 v = *(const bf16x2*)(h + (size_t)nb[e] * D + off);
    a0x += (float)v[0]; a0y += (float)v[1];
  }
  a0x += a1x + a2x + a3x;
  a0y += a1y + a2y + a3y;
  bf16x2 o;
  o[0] = (bf16_t)a0x; o[1] = (bf16_t)a0y;
  *(bf16x2*)(z + (size_t)node * D + off) = o;
}

// ===========================================================================
// gemm1_stats: GEMM1 (Z @ W1 + b1) -> BN column stats ONLY. No Y write —
// mlp2r recomputes GEMM1 bit-identically (1 us of MFMA vs 12.8 MB of Yf
// write traffic; R2-R4 proved the in-kernel grid barrier costs ~50 us of
// unexplained idle, so the kernel boundary IS our grid barrier).
// ===========================================================================
__global__ __launch_bounds__(256) void gemm1_stats(
    const bf16_t* __restrict__ Z, const bf16_t* __restrict__ Wsw1,
    const float* __restrict__ bias1, float* __restrict__ stats,
    int nStrips, int N) {
  __shared__ float sred[256];
  const int t = threadIdx.x;
  const int lane = t & 63;
  const int l15 = lane & 15;
  const int quad = lane >> 4;
  const int strip = blockIdx.x * 4 + (t >> 6);
  const bool active = strip < nStrips;

  sred[t] = 0.f;
  __syncthreads();

  bf16x8 a[4];
  const int row = strip * 16 + l15;
  if (active && row < N) {
#pragma unroll
    for (int kc = 0; kc < 4; ++kc)
      a[kc] = *(const bf16x8*)(Z + (size_t)row * D + kc * 32 + quad * 8);
  } else {
#pragma unroll
    for (int kc = 0; kc < 4; ++kc)
#pragma unroll
      for (int j = 0; j < 8; ++j) a[kc][j] = (bf16_t)0.f;
  }

  floatx4 acc[8];
#pragma unroll
  for (int nt = 0; nt < 8; ++nt) {
    float bv = bias1[nt * 16 + l15];
    acc[nt] = (floatx4){bv, bv, bv, bv};
  }
#pragma unroll
  for (int nt = 0; nt < 8; ++nt) {
#pragma unroll
    for (int kc = 0; kc < 4; ++kc) {
      bf16x8 b = *(const bf16x8*)(Wsw1 + (size_t)((nt * 4 + kc) * 64 + lane) * 8);
      acc[nt] = __builtin_amdgcn_mfma_f32_16x16x32_bf16(a[kc], b, acc[nt], 0, 0, 0);
    }
  }

  // BN stats: C/D layout col = nt*16+l15, row = quad*4+r
  const int rowBase = strip * 16 + quad * 4;
#pragma unroll
  for (int nt = 0; nt < 8; ++nt) {
    int c = nt * 16 + l15;
    float s = 0.f, q = 0.f;
    if (active) {
#pragma unroll
      for (int r = 0; r < 4; ++r) {
        if (rowBase + r < N) {
          float v = acc[nt][r];
          s += v; q += v * v;
        }
      }
    }
    s += __shfl_xor(s, 16); s += __shfl_xor(s, 32);
    q += __shfl_xor(q, 16); q += __shfl_xor(q, 32);
    if (quad == 0) {
      atomicAdd(&sred[c], s);
      atomicAdd(&sred[128 + c], q);
    }
  }
  __syncthreads();
  atomicAdd(&stats[t], sred[t]);
}

// ===========================================================================
// mlp2r: recompute GEMM1 from Z (bit-identical to gemm1_stats) -> BN+ReLU
// in C-layout (per-column coeff == per-nt) -> LDS transpose to A-frags ->
// GEMM2 -> store. All waves run all barriers; only global stores are guarded.
// ===========================================================================
__global__ __launch_bounds__(256) void mlp2r(
    const bf16_t* __restrict__ Z, const float* __restrict__ stats,
    const float* __restrict__ gamma, const float* __restrict__ beta,
    const bf16_t* __restrict__ Wsw1, const float* __restrict__ bias1,
    const bf16_t* __restrict__ Wsw2, const float* __restrict__ bias2,
    void* __restrict__ outp, int nStrips, int N, float invN,
    int relu_out, int fp32_out) {
  __shared__ bf16_t T[64][136];
  __shared__ float abL[256];
  const int t = threadIdx.x;
  const int wv = t >> 6;
  const int lane = t & 63;
  const int l15 = lane & 15;
  const int quad = lane >> 4;
  const int strip = blockIdx.x * 4 + wv;
  const bool active = strip < nStrips;

  // BN coefficients from the previous kernel's stats
  if (t < 128) {
    float mu = stats[t] * invN;
    float var = fmaxf(stats[128 + t] * invN - mu * mu, 0.f);
    float ai = gamma[t] * rsqrtf(var + BN_EPS);
    abL[t] = ai;
    abL[128 + t] = beta[t] - mu * ai;
  }

  // ---- GEMM1 recompute ----
  bf16x8 a[4];
  const int row = strip * 16 + l15;
  if (active && row < N) {
#pragma unroll
    for (int kc = 0; kc < 4; ++kc)
      a[kc] = *(const bf16x8*)(Z + (size_t)row * D + kc * 32 + quad * 8);
  } else {
#pragma unroll
    for (int kc = 0; kc < 4; ++kc)
#pragma unroll
      for (int j = 0; j < 8; ++j) a[kc][j] = (bf16_t)0.f;
  }

  floatx4 acc[8];
#pragma unroll
  for (int nt = 0; nt < 8; ++nt) {
    float bv = bias1[nt * 16 + l15];
    acc[nt] = (floatx4){bv, bv, bv, bv};
  }
#pragma unroll
  for (int nt = 0; nt < 8; ++nt) {
#pragma unroll
    for (int kc = 0; kc < 4; ++kc) {
      bf16x8 b = *(const bf16x8*)(Wsw1 + (size_t)((nt * 4 + kc) * 64 + lane) * 8);
      acc[nt] = __builtin_amdgcn_mfma_f32_16x16x32_bf16(a[kc], b, acc[nt], 0, 0, 0);
    }
  }

  __syncthreads();   // abL ready

  // ---- BN+ReLU in C-layout, transpose to A-frag order via LDS ----
  float bnA[8], bnB[8];
#pragma unroll
  for (int nt = 0; nt < 8; ++nt) {
    int c = nt * 16 + l15;
    bnA[nt] = abL[c];
    bnB[nt] = abL[128 + c];
  }

  const int lr = wv * 16 + quad * 4;
#pragma unroll
  for (int nt = 0; nt < 8; ++nt) {
    int c = nt * 16 + l15;
#pragma unroll
    for (int r = 0; r < 4; ++r)
      T[lr + r][c] = (bf16_t)fmaxf(fmaf(acc[nt][r], bnA[nt], bnB[nt]), 0.f);
  }
  __syncthreads();

  bf16x8 a2[4];
#pragma unroll
  for (int kc = 0; kc < 4; ++kc)
    a2[kc] = *(const bf16x8*)&T[wv * 16 + l15][kc * 32 + quad * 8];

  // ---- GEMM2 ----
#pragma unroll
  for (int nt = 0; nt < 8; ++nt) {
    float bv = bias2[nt * 16 + l15];
    acc[nt] = (floatx4){bv, bv, bv, bv};
  }
#pragma unroll
  for (int nt = 0; nt < 8; ++nt) {
#pragma unroll
    for (int kc = 0; kc < 4; ++kc) {
      bf16x8 b = *(const bf16x8*)(Wsw2 + (size_t)((nt * 4 + kc) * 64 + lane) * 8);
      acc[nt] = __builtin_amdgcn_mfma_f32_16x16x32_bf16(a2[kc], b, acc[nt], 0, 0, 0);
    }
  }

  if (!active) return;
  const int rowBase = strip * 16 + quad * 4;
  if (fp32_out) {
    float* out = (float*)outp;
#pragma unroll
    for (int nt = 0; nt < 8; ++nt) {
      int c = nt * 16 + l15;
#pragma unroll
      for (int r = 0; r < 4; ++r) {
        int rw = rowBase + r;
        if (rw < N) {
          float v = acc[nt][r];
          if (relu_out) v = fmaxf(v, 0.f);
          out[(size_t)rw * D + c] = v;
        }
      }
    }
  } else {
    bf16_t* out = (bf16_t*)outp;
#pragma unroll
    for (int nt = 0; nt < 8; ++nt) {
      int c = nt * 16 + l15;
#pragma unroll
      for (int r = 0; r < 4; ++r) {
        int rw = rowBase + r;
        if (rw < N) {
          float v = acc[nt][r];
          if (relu_out) v = fmaxf(v, 0.f);
          out[(size_t)rw * D + c] = (bf16_t)v;
        }
      }
    }
  }
}

// ===========================================================================
extern "C" void kernel_launch(void* const* d_in, const int* in_sizes, int n_in,
                              void* d_out, int out_size, void* d_ws, size_t ws_size,
                              hipStream_t stream) {
  const float* x     = (const float*)d_in[0];
  const float* W1    = (const float*)d_in[1];
  const float* b1    = (const float*)d_in[2];
  const float* gamma = (const float*)d_in[3];
  const float* beta  = (const float*)d_in[4];
  const float* W2    = (const float*)d_in[5];
  const float* b2    = (const float*)d_in[6];
  const int*   ei    = (const int*)d_in[7];

  const int N = in_sizes[0] / D;
  const int E = in_sizes[7] / 2;
  const int* src = ei;
  const int* dst = ei + E;

  char* ws = (char*)d_ws;
  size_t bufBytes = (size_t)N * D * sizeof(bf16_t);        // 12.8 MB
  bf16_t* hb   = (bf16_t*)ws;                               // h (bf16)
  bf16_t* zb   = (bf16_t*)(ws + bufBytes);                  // z (bf16)
  int*    ell  = (int*)(ws + 2 * bufBytes);                 // N*64 int = 12.8 MB
  int*    deg  = (int*)((char*)ell + (size_t)N * ELLW * sizeof(int));
  float*  stats = (float*)((char*)deg + (size_t)N * sizeof(int));   // 768 floats
  bf16_t* Wsw  = (bf16_t*)(stats + 768);                    // 6*16384 bf16

  const int n4 = N * D / 4;
  const int prepBlocks = (n4 + 255) / 256;
  const int eb = (E + 255) / 256;
  const int aggBlocks = (N + 3) / 4;
  const int nStrips = (N + 15) / 16;
  const int gemmBlocks = (nStrips + 3) / 4;
  const float invN = 1.f / (float)N;

  prep<<<prepBlocks, 256, 0, stream>>>(x, hb, W1, W2, Wsw, deg, stats, N, n4);
  ell_fill<<<eb, 256, 0, stream>>>(src, dst, deg, ell, E);

  for (int i = 0; i < 3; ++i) {
    float* st = stats + (size_t)i * 256;
    aggregate<<<aggBlocks, 256, 0, stream>>>(hb, zb, ell, deg, N);
    gemm1_stats<<<gemmBlocks, 256, 0, stream>>>(
        zb, Wsw + (size_t)i * 16384, b1 + (size_t)i * D, st, nStrips, N);
    void* Ob = (i == 2) ? d_out : (void*)hb;
    mlp2r<<<gemmBlocks, 256, 0, stream>>>(
        zb, st, gamma + (size_t)i * D, beta + (size_t)i * D,
        Wsw + (size_t)i * 16384, b1 + (size_t)i * D,
        Wsw + (size_t)(i + 3) * 16384, b2 + (size_t)i * D,
        Ob, nStrips, N, invN, (i < 2) ? 1 : 0, (i == 2) ? 1 : 0);
  }
}

// Round 6
// 301.265 us; speedup vs baseline: 1.4734x; 1.1594x over previous
//
#include <hip/hip_runtime.h>

#define D 128
#define BN_EPS 1e-5f
#define ELLW 64             // max degree slots (Poisson(12.8): P(deg>64) ~ 1e-24)
#define SGRP 8              // stats accumulator groups (= #XCDs; blockIdx%8 ~ XCD)

typedef __bf16 bf16_t;
typedef __bf16 bf16x8 __attribute__((ext_vector_type(8)));
typedef __bf16 bf16x4 __attribute__((ext_vector_type(4)));
typedef __bf16 bf16x2 __attribute__((ext_vector_type(2)));
typedef float floatx4 __attribute__((ext_vector_type(4)));

// ===========================================================================
// prep: zero deg[N] + stats[3*SGRP*256], x fp32 -> hb bf16, swizzle weights
// to MFMA B-frag order. Grid covers n4 = N*D/4 (largest range).
// ===========================================================================
__global__ void prep(const float* __restrict__ x, bf16_t* __restrict__ hb,
                     const float* __restrict__ W1, const float* __restrict__ W2,
                     bf16_t* __restrict__ Wsw, int* __restrict__ deg,
                     float* __restrict__ stats, int N, int n4) {
  int i = blockIdx.x * blockDim.x + threadIdx.x;
  if (i < n4) {
    float4 v = ((const float4*)x)[i];
    bf16x4 p;
    p[0] = (bf16_t)v.x; p[1] = (bf16_t)v.y; p[2] = (bf16_t)v.z; p[3] = (bf16_t)v.w;
    *(bf16x4*)(hb + (size_t)4 * i) = p;
  }
  if (i < N) deg[i] = 0;
  if (i < 3 * SGRP * 256) stats[i] = 0.f;
  if (i < 6 * 16384) {
    // B-frag order: lane = quad*16 + (n&15) holds B[k=kc*32+quad*8+j][n]
    int mat = i >> 14;
    int kn = i & 16383;
    int k = kn >> 7;
    int n = kn & 127;
    const float* Wm = (mat < 3) ? (W1 + (size_t)mat * 16384)
                                : (W2 + (size_t)(mat - 3) * 16384);
    float v = Wm[kn];
    int f = ((n >> 4) << 2) | (k >> 5);
    int ln = (((k >> 3) & 3) << 4) | (n & 15);
    int j = k & 7;
    Wsw[(size_t)mat * 16384 + ((f << 6) + ln) * 8 + j] = (bf16_t)v;
  }
}

// ===========================================================================
// ell_fill: one-shot ELL build — atomic slot bump + native 4B scatter.
// ===========================================================================
__global__ void ell_fill(const int* __restrict__ src, const int* __restrict__ dst,
                         int* __restrict__ deg, int* __restrict__ ell, int E) {
  int e = blockIdx.x * blockDim.x + threadIdx.x;
  if (e < E) {
    int d = dst[e];
    int slot = atomicAdd(&deg[d], 1);
    if (slot < ELLW) ell[(size_t)d * ELLW + slot] = src[e];
  }
}

// ===========================================================================
// aggregate: z[v] = h[v] + sum_{u in N(v)} h[u].
// TWO nodes per wave (half-wave of 32 lanes per node, bf16x4 = 8B/lane):
// same 256B/row coalescing, 2 independent gather streams per wave ->
// doubles outstanding loads per resident wave (gather is latency-bound:
// ~3 TB/s observed on L3-resident rows, far under L2/L3 capability).
// ===========================================================================
__global__ __launch_bounds__(256) void aggregate(
    const bf16_t* __restrict__ h, bf16_t* __restrict__ z,
    const int* __restrict__ ell, const int* __restrict__ deg, int Nn) {
  int node = blockIdx.x * 8 + (threadIdx.x >> 5);
  if (node >= Nn) return;
  int s = threadIdx.x & 31;
  int off = s << 2;                  // 4 bf16 = 8 B per lane
  int dg = deg[node]; if (dg > ELLW) dg = ELLW;
  const int* nb = ell + (size_t)node * ELLW;

  bf16x4 sv = *(const bf16x4*)(h + (size_t)node * D + off);
  floatx4 A0 = {(float)sv[0], (float)sv[1], (float)sv[2], (float)sv[3]};
  floatx4 A1 = {0.f, 0.f, 0.f, 0.f};
  floatx4 A2 = {0.f, 0.f, 0.f, 0.f};
  floatx4 A3 = {0.f, 0.f, 0.f, 0.f};
  int e = 0;
  for (; e + 4 <= dg; e += 4) {
    int4 i4 = *(const int4*)(nb + e);
    bf16x4 v0 = *(const bf16x4*)(h + (size_t)i4.x * D + off);
    bf16x4 v1 = *(const bf16x4*)(h + (size_t)i4.y * D + off);
    bf16x4 v2 = *(const bf16x4*)(h + (size_t)i4.z * D + off);
    bf16x4 v3 = *(const bf16x4*)(h + (size_t)i4.w * D + off);
#pragma unroll
    for (int j = 0; j < 4; ++j) {
      A0[j] += (float)v0[j];
      A1[j] += (float)v1[j];
      A2[j] += (float)v2[j];
      A3[j] += (float)v3[j];
    }
  }
  for (; e < dg; ++e) {
    bf16x4 v = *(const bf16x4*)(h + (size_t)nb[e] * D + off);
#pragma unroll
    for (int j = 0; j < 4; ++j) A0[j] += (float)v[j];
  }
#pragma unroll
  for (int j = 0; j < 4; ++j) A0[j] += A1[j] + A2[j] + A3[j];
  bf16x4 o;
  o[0] = (bf16_t)A0[0]; o[1] = (bf16_t)A0[1];
  o[2] = (bf16_t)A0[2]; o[3] = (bf16_t)A0[3];
  *(bf16x4*)(z + (size_t)node * D + off) = o;
}

// ===========================================================================
// gemm1_stats: GEMM1 (Z @ W1 + b1) -> BN column stats ONLY (no Y write;
// mlp2r recomputes GEMM1 bit-identically).
// Stats atomics go to stats[blockIdx%8][256]: R4's padding experiment showed
// cost scales with total CROSS-XCD same-address RMWs (line migration among
// 8 non-coherent L2s), not per-line serialization. blockIdx%8 ~ XCD
// round-robin -> atomics stay XCD-local; worst case still 8x less contention.
// ===========================================================================
__global__ __launch_bounds__(256) void gemm1_stats(
    const bf16_t* __restrict__ Z, const bf16_t* __restrict__ Wsw1,
    const float* __restrict__ bias1, float* __restrict__ stats,
    int nStrips, int N) {
  __shared__ float sred[256];
  const int t = threadIdx.x;
  const int lane = t & 63;
  const int l15 = lane & 15;
  const int quad = lane >> 4;
  const int strip = blockIdx.x * 4 + (t >> 6);
  const bool active = strip < nStrips;

  sred[t] = 0.f;
  __syncthreads();

  bf16x8 a[4];
  const int row = strip * 16 + l15;
  if (active && row < N) {
#pragma unroll
    for (int kc = 0; kc < 4; ++kc)
      a[kc] = *(const bf16x8*)(Z + (size_t)row * D + kc * 32 + quad * 8);
  } else {
#pragma unroll
    for (int kc = 0; kc < 4; ++kc)
#pragma unroll
      for (int j = 0; j < 8; ++j) a[kc][j] = (bf16_t)0.f;
  }

  floatx4 acc[8];
#pragma unroll
  for (int nt = 0; nt < 8; ++nt) {
    float bv = bias1[nt * 16 + l15];
    acc[nt] = (floatx4){bv, bv, bv, bv};
  }
#pragma unroll
  for (int nt = 0; nt < 8; ++nt) {
#pragma unroll
    for (int kc = 0; kc < 4; ++kc) {
      bf16x8 b = *(const bf16x8*)(Wsw1 + (size_t)((nt * 4 + kc) * 64 + lane) * 8);
      acc[nt] = __builtin_amdgcn_mfma_f32_16x16x32_bf16(a[kc], b, acc[nt], 0, 0, 0);
    }
  }

  // BN stats: C/D layout col = nt*16+l15, row = quad*4+r
  const int rowBase = strip * 16 + quad * 4;
#pragma unroll
  for (int nt = 0; nt < 8; ++nt) {
    int c = nt * 16 + l15;
    float s = 0.f, q = 0.f;
    if (active) {
#pragma unroll
      for (int r = 0; r < 4; ++r) {
        if (rowBase + r < N) {
          float v = acc[nt][r];
          s += v; q += v * v;
        }
      }
    }
    s += __shfl_xor(s, 16); s += __shfl_xor(s, 32);
    q += __shfl_xor(q, 16); q += __shfl_xor(q, 32);
    if (quad == 0) {
      atomicAdd(&sred[c], s);
      atomicAdd(&sred[128 + c], q);
    }
  }
  __syncthreads();
  atomicAdd(&stats[((blockIdx.x & (SGRP - 1)) << 8) + t], sred[t]);
}

// ===========================================================================
// mlp2r: sum SGRP stats partials -> BN coeffs; recompute GEMM1 from Z
// (bit-identical) -> BN+ReLU in C-layout -> LDS transpose to A-frags ->
// GEMM2 -> store. All waves run all barriers; only global stores guarded.
// ===========================================================================
__global__ __launch_bounds__(256) void mlp2r(
    const bf16_t* __restrict__ Z, const float* __restrict__ stats,
    const float* __restrict__ gamma, const float* __restrict__ beta,
    const bf16_t* __restrict__ Wsw1, const float* __restrict__ bias1,
    const bf16_t* __restrict__ Wsw2, const float* __restrict__ bias2,
    void* __restrict__ outp, int nStrips, int N, float invN,
    int relu_out, int fp32_out) {
  __shared__ bf16_t T[64][136];
  __shared__ float abL[256];
  const int t = threadIdx.x;
  const int wv = t >> 6;
  const int lane = t & 63;
  const int l15 = lane & 15;
  const int quad = lane >> 4;
  const int strip = blockIdx.x * 4 + wv;
  const bool active = strip < nStrips;

  // BN coefficients: sum the SGRP per-XCD partials, then fold
  if (t < 128) {
    float s0 = 0.f, q0 = 0.f;
#pragma unroll
    for (int g = 0; g < SGRP; ++g) {
      s0 += stats[(g << 8) + t];
      q0 += stats[(g << 8) + 128 + t];
    }
    float mu = s0 * invN;
    float var = fmaxf(q0 * invN - mu * mu, 0.f);
    float ai = gamma[t] * rsqrtf(var + BN_EPS);
    abL[t] = ai;
    abL[128 + t] = beta[t] - mu * ai;
  }

  // ---- GEMM1 recompute ----
  bf16x8 a[4];
  const int row = strip * 16 + l15;
  if (active && row < N) {
#pragma unroll
    for (int kc = 0; kc < 4; ++kc)
      a[kc] = *(const bf16x8*)(Z + (size_t)row * D + kc * 32 + quad * 8);
  } else {
#pragma unroll
    for (int kc = 0; kc < 4; ++kc)
#pragma unroll
      for (int j = 0; j < 8; ++j) a[kc][j] = (bf16_t)0.f;
  }

  floatx4 acc[8];
#pragma unroll
  for (int nt = 0; nt < 8; ++nt) {
    float bv = bias1[nt * 16 + l15];
    acc[nt] = (floatx4){bv, bv, bv, bv};
  }
#pragma unroll
  for (int nt = 0; nt < 8; ++nt) {
#pragma unroll
    for (int kc = 0; kc < 4; ++kc) {
      bf16x8 b = *(const bf16x8*)(Wsw1 + (size_t)((nt * 4 + kc) * 64 + lane) * 8);
      acc[nt] = __builtin_amdgcn_mfma_f32_16x16x32_bf16(a[kc], b, acc[nt], 0, 0, 0);
    }
  }

  __syncthreads();   // abL ready

  // ---- BN+ReLU in C-layout, transpose to A-frag order via LDS ----
  float bnA[8], bnB[8];
#pragma unroll
  for (int nt = 0; nt < 8; ++nt) {
    int c = nt * 16 + l15;
    bnA[nt] = abL[c];
    bnB[nt] = abL[128 + c];
  }

  const int lr = wv * 16 + quad * 4;
#pragma unroll
  for (int nt = 0; nt < 8; ++nt) {
    int c = nt * 16 + l15;
#pragma unroll
    for (int r = 0; r < 4; ++r)
      T[lr + r][c] = (bf16_t)fmaxf(fmaf(acc[nt][r], bnA[nt], bnB[nt]), 0.f);
  }
  __syncthreads();

  bf16x8 a2[4];
#pragma unroll
  for (int kc = 0; kc < 4; ++kc)
    a2[kc] = *(const bf16x8*)&T[wv * 16 + l15][kc * 32 + quad * 8];

  // ---- GEMM2 ----
#pragma unroll
  for (int nt = 0; nt < 8; ++nt) {
    float bv = bias2[nt * 16 + l15];
    acc[nt] = (floatx4){bv, bv, bv, bv};
  }
#pragma unroll
  for (int nt = 0; nt < 8; ++nt) {
#pragma unroll
    for (int kc = 0; kc < 4; ++kc) {
      bf16x8 b = *(const bf16x8*)(Wsw2 + (size_t)((nt * 4 + kc) * 64 + lane) * 8);
      acc[nt] = __builtin_amdgcn_mfma_f32_16x16x32_bf16(a2[kc], b, acc[nt], 0, 0, 0);
    }
  }

  if (!active) return;
  const int rowBase = strip * 16 + quad * 4;
  if (fp32_out) {
    float* out = (float*)outp;
#pragma unroll
    for (int nt = 0; nt < 8; ++nt) {
      int c = nt * 16 + l15;
#pragma unroll
      for (int r = 0; r < 4; ++r) {
        int rw = rowBase + r;
        if (rw < N) {
          float v = acc[nt][r];
          if (relu_out) v = fmaxf(v, 0.f);
          out[(size_t)rw * D + c] = v;
        }
      }
    }
  } else {
    bf16_t* out = (bf16_t*)outp;
#pragma unroll
    for (int nt = 0; nt < 8; ++nt) {
      int c = nt * 16 + l15;
#pragma unroll
      for (int r = 0; r < 4; ++r) {
        int rw = rowBase + r;
        if (rw < N) {
          float v = acc[nt][r];
          if (relu_out) v = fmaxf(v, 0.f);
          out[(size_t)rw * D + c] = (bf16_t)v;
        }
      }
    }
  }
}

// ===========================================================================
extern "C" void kernel_launch(void* const* d_in, const int* in_sizes, int n_in,
                              void* d_out, int out_size, void* d_ws, size_t ws_size,
                              hipStream_t stream) {
  const float* x     = (const float*)d_in[0];
  const float* W1    = (const float*)d_in[1];
  const float* b1    = (const float*)d_in[2];
  const float* gamma = (const float*)d_in[3];
  const float* beta  = (const float*)d_in[4];
  const float* W2    = (const float*)d_in[5];
  const float* b2    = (const float*)d_in[6];
  const int*   ei    = (const int*)d_in[7];

  const int N = in_sizes[0] / D;
  const int E = in_sizes[7] / 2;
  const int* src = ei;
  const int* dst = ei + E;

  char* ws = (char*)d_ws;
  size_t bufBytes = (size_t)N * D * sizeof(bf16_t);        // 12.8 MB
  bf16_t* hb   = (bf16_t*)ws;                               // h (bf16)
  bf16_t* zb   = (bf16_t*)(ws + bufBytes);                  // z (bf16)
  int*    ell  = (int*)(ws + 2 * bufBytes);                 // N*64 int = 12.8 MB
  int*    deg  = (int*)((char*)ell + (size_t)N * ELLW * sizeof(int));
  float*  stats = (float*)((char*)deg + (size_t)N * sizeof(int)); // 3*SGRP*256
  bf16_t* Wsw  = (bf16_t*)(stats + 3 * SGRP * 256);         // 6*16384 bf16

  const int n4 = N * D / 4;
  const int prepBlocks = (n4 + 255) / 256;
  const int eb = (E + 255) / 256;
  const int aggBlocks = (N + 7) / 8;
  const int nStrips = (N + 15) / 16;
  const int gemmBlocks = (nStrips + 3) / 4;
  const float invN = 1.f / (float)N;

  prep<<<prepBlocks, 256, 0, stream>>>(x, hb, W1, W2, Wsw, deg, stats, N, n4);
  ell_fill<<<eb, 256, 0, stream>>>(src, dst, deg, ell, E);

  for (int i = 0; i < 3; ++i) {
    float* st = stats + (size_t)i * SGRP * 256;
    aggregate<<<aggBlocks, 256, 0, stream>>>(hb, zb, ell, deg, N);
    gemm1_stats<<<gemmBlocks, 256, 0, stream>>>(
        zb, Wsw + (size_t)i * 16384, b1 + (size_t)i * D, st, nStrips, N);
    void* Ob = (i == 2) ? d_out : (void*)hb;
    mlp2r<<<gemmBlocks, 256, 0, stream>>>(
        zb, st, gamma + (size_t)i * D, beta + (size_t)i * D,
        Wsw + (size_t)i * 16384, b1 + (size_t)i * D,
        Wsw + (size_t)(i + 3) * 16384, b2 + (size_t)i * D,
        Ob, nStrips, N, invN, (i < 2) ? 1 : 0, (i == 2) ? 1 : 0);
  }
}

// Round 7
// 297.333 us; speedup vs baseline: 1.4929x; 1.0132x over previous
//
#include <hip/hip_runtime.h>

#define D 128
#define BN_EPS 1e-5f
#define ELLW 64             // max degree slots (Poisson(12.8): P(deg>64) ~ 1e-24)
#define SGRP 8              // stats accumulator groups (= #XCDs; blockIdx%8 ~ XCD)

typedef __bf16 bf16_t;
typedef __bf16 bf16x8 __attribute__((ext_vector_type(8)));
typedef __bf16 bf16x4 __attribute__((ext_vector_type(4)));
typedef __bf16 bf16x2 __attribute__((ext_vector_type(2)));
typedef float floatx4 __attribute__((ext_vector_type(4)));

// ===========================================================================
// prep: zero deg[N] + stats[3*SGRP*256], x fp32 -> hb bf16, swizzle weights
// to MFMA B-frag order. Grid covers n4 = N*D/4 (largest range).
// ===========================================================================
__global__ void prep(const float* __restrict__ x, bf16_t* __restrict__ hb,
                     const float* __restrict__ W1, const float* __restrict__ W2,
                     bf16_t* __restrict__ Wsw, int* __restrict__ deg,
                     float* __restrict__ stats, int N, int n4) {
  int i = blockIdx.x * blockDim.x + threadIdx.x;
  if (i < n4) {
    float4 v = ((const float4*)x)[i];
    bf16x4 p;
    p[0] = (bf16_t)v.x; p[1] = (bf16_t)v.y; p[2] = (bf16_t)v.z; p[3] = (bf16_t)v.w;
    *(bf16x4*)(hb + (size_t)4 * i) = p;
  }
  if (i < N) deg[i] = 0;
  if (i < 3 * SGRP * 256) stats[i] = 0.f;
  if (i < 6 * 16384) {
    // B-frag order: lane = quad*16 + (n&15) holds B[k=kc*32+quad*8+j][n]
    int mat = i >> 14;
    int kn = i & 16383;
    int k = kn >> 7;
    int n = kn & 127;
    const float* Wm = (mat < 3) ? (W1 + (size_t)mat * 16384)
                                : (W2 + (size_t)(mat - 3) * 16384);
    float v = Wm[kn];
    int f = ((n >> 4) << 2) | (k >> 5);
    int ln = (((k >> 3) & 3) << 4) | (n & 15);
    int j = k & 7;
    Wsw[(size_t)mat * 16384 + ((f << 6) + ln) * 8 + j] = (bf16_t)v;
  }
}

// ===========================================================================
// ell_fill: one-shot ELL build — atomic slot bump + native 4B scatter.
// ===========================================================================
__global__ void ell_fill(const int* __restrict__ src, const int* __restrict__ dst,
                         int* __restrict__ deg, int* __restrict__ ell, int E) {
  int e = blockIdx.x * blockDim.x + threadIdx.x;
  if (e < E) {
    int d = dst[e];
    int slot = atomicAdd(&deg[d], 1);
    if (slot < ELLW) ell[(size_t)d * ELLW + slot] = src[e];
  }
}

// ===========================================================================
// aggregate: z[v] = h[v] + sum_{u in N(v)} h[u].
// TWO nodes per wave (half-wave of 32 lanes per node, bf16x4 = 8B/lane)
// + 8-DEEP per-stream pipeline: the gather is latency-bound on L3-resident
// rows (~3-4 TB/s effective), so outstanding row-loads per resident wave is
// the throughput knob. VGPR stays <=64 -> 8 waves/SIMD occupancy preserved.
// deg~12.8: typical node = one 8-iter + one 4-iter + ~1 tail.
// ===========================================================================
__global__ __launch_bounds__(256) void aggregate(
    const bf16_t* __restrict__ h, bf16_t* __restrict__ z,
    const int* __restrict__ ell, const int* __restrict__ deg, int Nn) {
  int node = blockIdx.x * 8 + (threadIdx.x >> 5);
  if (node >= Nn) return;
  int s = threadIdx.x & 31;
  int off = s << 2;                  // 4 bf16 = 8 B per lane
  int dg = deg[node]; if (dg > ELLW) dg = ELLW;
  const int* nb = ell + (size_t)node * ELLW;

  bf16x4 sv = *(const bf16x4*)(h + (size_t)node * D + off);
  floatx4 A0 = {(float)sv[0], (float)sv[1], (float)sv[2], (float)sv[3]};
  floatx4 A1 = {0.f, 0.f, 0.f, 0.f};
  floatx4 A2 = {0.f, 0.f, 0.f, 0.f};
  floatx4 A3 = {0.f, 0.f, 0.f, 0.f};
  int e = 0;
  for (; e + 8 <= dg; e += 8) {
    int4 ia = *(const int4*)(nb + e);
    int4 ib = *(const int4*)(nb + e + 4);
    bf16x4 v0 = *(const bf16x4*)(h + (size_t)ia.x * D + off);
    bf16x4 v1 = *(const bf16x4*)(h + (size_t)ia.y * D + off);
    bf16x4 v2 = *(const bf16x4*)(h + (size_t)ia.z * D + off);
    bf16x4 v3 = *(const bf16x4*)(h + (size_t)ia.w * D + off);
    bf16x4 v4 = *(const bf16x4*)(h + (size_t)ib.x * D + off);
    bf16x4 v5 = *(const bf16x4*)(h + (size_t)ib.y * D + off);
    bf16x4 v6 = *(const bf16x4*)(h + (size_t)ib.z * D + off);
    bf16x4 v7 = *(const bf16x4*)(h + (size_t)ib.w * D + off);
#pragma unroll
    for (int j = 0; j < 4; ++j) {
      A0[j] += (float)v0[j];
      A1[j] += (float)v1[j];
      A2[j] += (float)v2[j];
      A3[j] += (float)v3[j];
      A0[j] += (float)v4[j];
      A1[j] += (float)v5[j];
      A2[j] += (float)v6[j];
      A3[j] += (float)v7[j];
    }
  }
  for (; e + 4 <= dg; e += 4) {
    int4 i4 = *(const int4*)(nb + e);
    bf16x4 v0 = *(const bf16x4*)(h + (size_t)i4.x * D + off);
    bf16x4 v1 = *(const bf16x4*)(h + (size_t)i4.y * D + off);
    bf16x4 v2 = *(const bf16x4*)(h + (size_t)i4.z * D + off);
    bf16x4 v3 = *(const bf16x4*)(h + (size_t)i4.w * D + off);
#pragma unroll
    for (int j = 0; j < 4; ++j) {
      A0[j] += (float)v0[j];
      A1[j] += (float)v1[j];
      A2[j] += (float)v2[j];
      A3[j] += (float)v3[j];
    }
  }
  for (; e < dg; ++e) {
    bf16x4 v = *(const bf16x4*)(h + (size_t)nb[e] * D + off);
#pragma unroll
    for (int j = 0; j < 4; ++j) A0[j] += (float)v[j];
  }
#pragma unroll
  for (int j = 0; j < 4; ++j) A0[j] += A1[j] + A2[j] + A3[j];
  bf16x4 o;
  o[0] = (bf16_t)A0[0]; o[1] = (bf16_t)A0[1];
  o[2] = (bf16_t)A0[2]; o[3] = (bf16_t)A0[3];
  *(bf16x4*)(z + (size_t)node * D + off) = o;
}

// ===========================================================================
// gemm1_stats: GEMM1 (Z @ W1 + b1) -> BN column stats ONLY (no Y write;
// mlp2r recomputes GEMM1 bit-identically).
// Stats atomics go to stats[blockIdx%8][256]: R4's padding experiment showed
// cost scales with total CROSS-XCD same-address RMWs (line migration among
// 8 non-coherent L2s), not per-line serialization. blockIdx%8 ~ XCD
// round-robin -> atomics stay XCD-local; worst case still 8x less contention.
// ===========================================================================
__global__ __launch_bounds__(256) void gemm1_stats(
    const bf16_t* __restrict__ Z, const bf16_t* __restrict__ Wsw1,
    const float* __restrict__ bias1, float* __restrict__ stats,
    int nStrips, int N) {
  __shared__ float sred[256];
  const int t = threadIdx.x;
  const int lane = t & 63;
  const int l15 = lane & 15;
  const int quad = lane >> 4;
  const int strip = blockIdx.x * 4 + (t >> 6);
  const bool active = strip < nStrips;

  sred[t] = 0.f;
  __syncthreads();

  bf16x8 a[4];
  const int row = strip * 16 + l15;
  if (active && row < N) {
#pragma unroll
    for (int kc = 0; kc < 4; ++kc)
      a[kc] = *(const bf16x8*)(Z + (size_t)row * D + kc * 32 + quad * 8);
  } else {
#pragma unroll
    for (int kc = 0; kc < 4; ++kc)
#pragma unroll
      for (int j = 0; j < 8; ++j) a[kc][j] = (bf16_t)0.f;
  }

  floatx4 acc[8];
#pragma unroll
  for (int nt = 0; nt < 8; ++nt) {
    float bv = bias1[nt * 16 + l15];
    acc[nt] = (floatx4){bv, bv, bv, bv};
  }
#pragma unroll
  for (int nt = 0; nt < 8; ++nt) {
#pragma unroll
    for (int kc = 0; kc < 4; ++kc) {
      bf16x8 b = *(const bf16x8*)(Wsw1 + (size_t)((nt * 4 + kc) * 64 + lane) * 8);
      acc[nt] = __builtin_amdgcn_mfma_f32_16x16x32_bf16(a[kc], b, acc[nt], 0, 0, 0);
    }
  }

  // BN stats: C/D layout col = nt*16+l15, row = quad*4+r
  const int rowBase = strip * 16 + quad * 4;
#pragma unroll
  for (int nt = 0; nt < 8; ++nt) {
    int c = nt * 16 + l15;
    float s = 0.f, q = 0.f;
    if (active) {
#pragma unroll
      for (int r = 0; r < 4; ++r) {
        if (rowBase + r < N) {
          float v = acc[nt][r];
          s += v; q += v * v;
        }
      }
    }
    s += __shfl_xor(s, 16); s += __shfl_xor(s, 32);
    q += __shfl_xor(q, 16); q += __shfl_xor(q, 32);
    if (quad == 0) {
      atomicAdd(&sred[c], s);
      atomicAdd(&sred[128 + c], q);
    }
  }
  __syncthreads();
  atomicAdd(&stats[((blockIdx.x & (SGRP - 1)) << 8) + t], sred[t]);
}

// ===========================================================================
// mlp2r: sum SGRP stats partials -> BN coeffs; recompute GEMM1 from Z
// (bit-identical) -> BN+ReLU in C-layout -> LDS transpose to A-frags ->
// GEMM2 -> store. All waves run all barriers; only global stores guarded.
// ===========================================================================
__global__ __launch_bounds__(256) void mlp2r(
    const bf16_t* __restrict__ Z, const float* __restrict__ stats,
    const float* __restrict__ gamma, const float* __restrict__ beta,
    const bf16_t* __restrict__ Wsw1, const float* __restrict__ bias1,
    const bf16_t* __restrict__ Wsw2, const float* __restrict__ bias2,
    void* __restrict__ outp, int nStrips, int N, float invN,
    int relu_out, int fp32_out) {
  __shared__ bf16_t T[64][136];
  __shared__ float abL[256];
  const int t = threadIdx.x;
  const int wv = t >> 6;
  const int lane = t & 63;
  const int l15 = lane & 15;
  const int quad = lane >> 4;
  const int strip = blockIdx.x * 4 + wv;
  const bool active = strip < nStrips;

  // BN coefficients: sum the SGRP per-XCD partials, then fold
  if (t < 128) {
    float s0 = 0.f, q0 = 0.f;
#pragma unroll
    for (int g = 0; g < SGRP; ++g) {
      s0 += stats[(g << 8) + t];
      q0 += stats[(g << 8) + 128 + t];
    }
    float mu = s0 * invN;
    float var = fmaxf(q0 * invN - mu * mu, 0.f);
    float ai = gamma[t] * rsqrtf(var + BN_EPS);
    abL[t] = ai;
    abL[128 + t] = beta[t] - mu * ai;
  }

  // ---- GEMM1 recompute ----
  bf16x8 a[4];
  const int row = strip * 16 + l15;
  if (active && row < N) {
#pragma unroll
    for (int kc = 0; kc < 4; ++kc)
      a[kc] = *(const bf16x8*)(Z + (size_t)row * D + kc * 32 + quad * 8);
  } else {
#pragma unroll
    for (int kc = 0; kc < 4; ++kc)
#pragma unroll
      for (int j = 0; j < 8; ++j) a[kc][j] = (bf16_t)0.f;
  }

  floatx4 acc[8];
#pragma unroll
  for (int nt = 0; nt < 8; ++nt) {
    float bv = bias1[nt * 16 + l15];
    acc[nt] = (floatx4){bv, bv, bv, bv};
  }
#pragma unroll
  for (int nt = 0; nt < 8; ++nt) {
#pragma unroll
    for (int kc = 0; kc < 4; ++kc) {
      bf16x8 b = *(const bf16x8*)(Wsw1 + (size_t)((nt * 4 + kc) * 64 + lane) * 8);
      acc[nt] = __builtin_amdgcn_mfma_f32_16x16x32_bf16(a[kc], b, acc[nt], 0, 0, 0);
    }
  }

  __syncthreads();   // abL ready

  // ---- BN+ReLU in C-layout, transpose to A-frag order via LDS ----
  float bnA[8], bnB[8];
#pragma unroll
  for (int nt = 0; nt < 8; ++nt) {
    int c = nt * 16 + l15;
    bnA[nt] = abL[c];
    bnB[nt] = abL[128 + c];
  }

  const int lr = wv * 16 + quad * 4;
#pragma unroll
  for (int nt = 0; nt < 8; ++nt) {
    int c = nt * 16 + l15;
#pragma unroll
    for (int r = 0; r < 4; ++r)
      T[lr + r][c] = (bf16_t)fmaxf(fmaf(acc[nt][r], bnA[nt], bnB[nt]), 0.f);
  }
  __syncthreads();

  bf16x8 a2[4];
#pragma unroll
  for (int kc = 0; kc < 4; ++kc)
    a2[kc] = *(const bf16x8*)&T[wv * 16 + l15][kc * 32 + quad * 8];

  // ---- GEMM2 ----
#pragma unroll
  for (int nt = 0; nt < 8; ++nt) {
    float bv = bias2[nt * 16 + l15];
    acc[nt] = (floatx4){bv, bv, bv, bv};
  }
#pragma unroll
  for (int nt = 0; nt < 8; ++nt) {
#pragma unroll
    for (int kc = 0; kc < 4; ++kc) {
      bf16x8 b = *(const bf16x8*)(Wsw2 + (size_t)((nt * 4 + kc) * 64 + lane) * 8);
      acc[nt] = __builtin_amdgcn_mfma_f32_16x16x32_bf16(a2[kc], b, acc[nt], 0, 0, 0);
    }
  }

  if (!active) return;
  const int rowBase = strip * 16 + quad * 4;
  if (fp32_out) {
    float* out = (float*)outp;
#pragma unroll
    for (int nt = 0; nt < 8; ++nt) {
      int c = nt * 16 + l15;
#pragma unroll
      for (int r = 0; r < 4; ++r) {
        int rw = rowBase + r;
        if (rw < N) {
          float v = acc[nt][r];
          if (relu_out) v = fmaxf(v, 0.f);
          out[(size_t)rw * D + c] = v;
        }
      }
    }
  } else {
    bf16_t* out = (bf16_t*)outp;
#pragma unroll
    for (int nt = 0; nt < 8; ++nt) {
      int c = nt * 16 + l15;
#pragma unroll
      for (int r = 0; r < 4; ++r) {
        int rw = rowBase + r;
        if (rw < N) {
          float v = acc[nt][r];
          if (relu_out) v = fmaxf(v, 0.f);
          out[(size_t)rw * D + c] = (bf16_t)v;
        }
      }
    }
  }
}

// ===========================================================================
extern "C" void kernel_launch(void* const* d_in, const int* in_sizes, int n_in,
                              void* d_out, int out_size, void* d_ws, size_t ws_size,
                              hipStream_t stream) {
  const float* x     = (const float*)d_in[0];
  const float* W1    = (const float*)d_in[1];
  const float* b1    = (const float*)d_in[2];
  const float* gamma = (const float*)d_in[3];
  const float* beta  = (const float*)d_in[4];
  const float* W2    = (const float*)d_in[5];
  const float* b2    = (const float*)d_in[6];
  const int*   ei    = (const int*)d_in[7];

  const int N = in_sizes[0] / D;
  const int E = in_sizes[7] / 2;
  const int* src = ei;
  const int* dst = ei + E;

  char* ws = (char*)d_ws;
  size_t bufBytes = (size_t)N * D * sizeof(bf16_t);        // 12.8 MB
  bf16_t* hb   = (bf16_t*)ws;                               // h (bf16)
  bf16_t* zb   = (bf16_t*)(ws + bufBytes);                  // z (bf16)
  int*    ell  = (int*)(ws + 2 * bufBytes);                 // N*64 int = 12.8 MB
  int*    deg  = (int*)((char*)ell + (size_t)N * ELLW * sizeof(int));
  float*  stats = (float*)((char*)deg + (size_t)N * sizeof(int)); // 3*SGRP*256
  bf16_t* Wsw  = (bf16_t*)(stats + 3 * SGRP * 256);         // 6*16384 bf16

  const int n4 = N * D / 4;
  const int prepBlocks = (n4 + 255) / 256;
  const int eb = (E + 255) / 256;
  const int aggBlocks = (N + 7) / 8;
  const int nStrips = (N + 15) / 16;
  const int gemmBlocks = (nStrips + 3) / 4;
  const float invN = 1.f / (float)N;

  prep<<<prepBlocks, 256, 0, stream>>>(x, hb, W1, W2, Wsw, deg, stats, N, n4);
  ell_fill<<<eb, 256, 0, stream>>>(src, dst, deg, ell, E);

  for (int i = 0; i < 3; ++i) {
    float* st = stats + (size_t)i * SGRP * 256;
    aggregate<<<aggBlocks, 256, 0, stream>>>(hb, zb, ell, deg, N);
    gemm1_stats<<<gemmBlocks, 256, 0, stream>>>(
        zb, Wsw + (size_t)i * 16384, b1 + (size_t)i * D, st, nStrips, N);
    void* Ob = (i == 2) ? d_out : (void*)hb;
    mlp2r<<<gemmBlocks, 256, 0, stream>>>(
        zb, st, gamma + (size_t)i * D, beta + (size_t)i * D,
        Wsw + (size_t)i * 16384, b1 + (size_t)i * D,
        Wsw + (size_t)(i + 3) * 16384, b2 + (size_t)i * D,
        Ob, nStrips, N, invN, (i < 2) ? 1 : 0, (i == 2) ? 1 : 0);
  }
}